// Round 1
// baseline (12995.056 us; speedup 1.0000x reference)
//
#include <hip/hip_runtime.h>
#include <hip/hip_bf16.h>
#include <math.h>

#define VOCAB 50257
#define DIM   768
#define NH    12
#define HSZ   64
#define NL    6
#define BB    2
#define TT    2048
#define BTOK  (BB*TT)
#define DFF   (4*DIM)
#define EPSL  1e-5f

// ---------------- embedding: x = tok_emb[idx] + pos_emb ----------------
__global__ __launch_bounds__(192) void embed_kernel(
    const int* __restrict__ idx, const float* __restrict__ tok,
    const float* __restrict__ pos, float* __restrict__ x)
{
  const int r = blockIdx.x;          // 0..BTOK-1
  const int t = r % TT;
  const int tokid = idx[r];
  const float4* tp = (const float4*)(tok + (size_t)tokid * DIM);
  const float4* pp = (const float4*)(pos + (size_t)t * DIM);
  float4* xp = (float4*)(x + (size_t)r * DIM);
  const int c = threadIdx.x;         // 192 * 4 = 768
  float4 a = tp[c], b = pp[c];
  xp[c] = make_float4(a.x + b.x, a.y + b.y, a.z + b.z, a.w + b.w);
}

// ---------------- block reduction helper (blockDim == 256) ----------------
__device__ __forceinline__ float block_reduce_sum(float v, float* sm)
{
#pragma unroll
  for (int o = 32; o > 0; o >>= 1) v += __shfl_down(v, o, 64);
  const int w = threadIdx.x >> 6;
  if ((threadIdx.x & 63) == 0) sm[w] = v;
  __syncthreads();
  const float r = sm[0] + sm[1] + sm[2] + sm[3];
  __syncthreads();
  return r;
}

// ---------------- layernorm (row per block, D = 768 = 3*256) ----------------
__global__ __launch_bounds__(256) void ln_kernel(
    const float* __restrict__ x, const float* __restrict__ gs,
    const float* __restrict__ gb, float* __restrict__ out)
{
  __shared__ float sm[4];
  const int r = blockIdx.x, tid = threadIdx.x;
  const float* xr = x + (size_t)r * DIM;
  const float v0 = xr[tid], v1 = xr[tid + 256], v2 = xr[tid + 512];
  const float mean = block_reduce_sum(v0 + v1 + v2, sm) * (1.0f / DIM);
  const float d0 = v0 - mean, d1 = v1 - mean, d2 = v2 - mean;
  const float var = block_reduce_sum(d0*d0 + d1*d1 + d2*d2, sm) * (1.0f / DIM);
  const float inv = rsqrtf(var + EPSL);
  float* orow = out + (size_t)r * DIM;
  orow[tid]       = d0 * inv * gs[tid]       + gb[tid];
  orow[tid + 256] = d1 * inv * gs[tid + 256] + gb[tid + 256];
  orow[tid + 512] = d2 * inv * gs[tid + 512] + gb[tid + 512];
}

// ---------------- tiled fp32 GEMM: C = act(A @ W + bias) (+ res) ------------
// 64x64 tile, BK=16, 256 threads, 4x4 micro-tile per thread.
// blockIdx.x = row tile (fastest -> consecutive blocks share the W stripe),
// blockIdx.y = col tile.
// QKV_W: W is [H, D, HS] accessed as W(d, c) = W[(c>>6)*K*64 + d*64 + (c&63)]
// TAIL : N not multiple of 4/64 (head GEMM) -> scalar guarded W loads+stores
template<bool QKV_W, bool TAIL, bool RELU, bool RES, bool BIAS>
__global__ __launch_bounds__(256) void gemm_kernel(
    const float* __restrict__ A, const float* __restrict__ W,
    const float* __restrict__ bias, const float* __restrict__ res,
    float* __restrict__ C, int M, int N, int K)
{
  __shared__ float As[16][68];   // A tile transposed: As[k][row]
  __shared__ float Ws[16][68];   // W tile: Ws[k][col]
  const int tid = threadIdx.x;
  const int ty = tid >> 4, tx = tid & 15;
  const int row0 = blockIdx.x * 64, col0 = blockIdx.y * 64;

  const int ar  = tid >> 2;          // 0..63  A row within tile
  const int akg = (tid & 3) << 2;    // 0,4,8,12  k group
  const int wr  = tid >> 4;          // 0..15  W k-row
  const int wc  = (tid & 15) << 2;   // 0..60  W col group

  float acc[4][4] = {};
  const float* Ap = A + (size_t)(row0 + ar) * K + akg;

  for (int k0 = 0; k0 < K; k0 += 16) {
    const float4 av = *(const float4*)(Ap + k0);
    float4 wv;
    if constexpr (QKV_W) {
      wv = *(const float4*)(W + (size_t)(col0 >> 6) * K * 64 +
                            (size_t)(k0 + wr) * 64 + wc);
    } else if constexpr (!TAIL) {
      wv = *(const float4*)(W + (size_t)(k0 + wr) * N + col0 + wc);
    } else {
      const float* wp = W + (size_t)(k0 + wr) * N + col0 + wc;
      const int c = col0 + wc;
      wv.x = (c + 0 < N) ? wp[0] : 0.f;
      wv.y = (c + 1 < N) ? wp[1] : 0.f;
      wv.z = (c + 2 < N) ? wp[2] : 0.f;
      wv.w = (c + 3 < N) ? wp[3] : 0.f;
    }
    __syncthreads();               // previous iteration's reads done
    As[akg + 0][ar] = av.x;
    As[akg + 1][ar] = av.y;
    As[akg + 2][ar] = av.z;
    As[akg + 3][ar] = av.w;
    *(float4*)&Ws[wr][wc] = wv;
    __syncthreads();
#pragma unroll
    for (int kk = 0; kk < 16; ++kk) {
      const float4 a = *(const float4*)&As[kk][ty << 2];
      const float4 w = *(const float4*)&Ws[kk][tx << 2];
      acc[0][0] += a.x * w.x; acc[0][1] += a.x * w.y;
      acc[0][2] += a.x * w.z; acc[0][3] += a.x * w.w;
      acc[1][0] += a.y * w.x; acc[1][1] += a.y * w.y;
      acc[1][2] += a.y * w.z; acc[1][3] += a.y * w.w;
      acc[2][0] += a.z * w.x; acc[2][1] += a.z * w.y;
      acc[2][2] += a.z * w.z; acc[2][3] += a.z * w.w;
      acc[3][0] += a.w * w.x; acc[3][1] += a.w * w.y;
      acc[3][2] += a.w * w.z; acc[3][3] += a.w * w.w;
    }
  }

  const int crow = row0 + (ty << 2);
  const int ccol = col0 + (tx << 2);
  if constexpr (!TAIL) {
    float4 bv = make_float4(0.f, 0.f, 0.f, 0.f);
    if constexpr (BIAS) bv = *(const float4*)(bias + ccol);
#pragma unroll
    for (int i = 0; i < 4; ++i) {
      float4 vv;
      vv.x = acc[i][0] + bv.x; vv.y = acc[i][1] + bv.y;
      vv.z = acc[i][2] + bv.z; vv.w = acc[i][3] + bv.w;
      if constexpr (RELU) {
        vv.x = fmaxf(vv.x, 0.f); vv.y = fmaxf(vv.y, 0.f);
        vv.z = fmaxf(vv.z, 0.f); vv.w = fmaxf(vv.w, 0.f);
      }
      if constexpr (RES) {
        const float4 rv = *(const float4*)(res + (size_t)(crow + i) * N + ccol);
        vv.x += rv.x; vv.y += rv.y; vv.z += rv.z; vv.w += rv.w;
      }
      *(float4*)(C + (size_t)(crow + i) * N + ccol) = vv;
    }
  } else {
#pragma unroll
    for (int i = 0; i < 4; ++i) {
#pragma unroll
      for (int j = 0; j < 4; ++j) {
        const int c = ccol + j;
        if (c < N) {
          float val = acc[i][j];
          if constexpr (BIAS) val += bias[c];
          if constexpr (RELU) val = fmaxf(val, 0.f);
          if constexpr (RES)  val += res[(size_t)(crow + i) * N + c];
          C[(size_t)(crow + i) * N + c] = val;
        }
      }
    }
  }
}

// ---------------- flash attention fp32, 64x64 tiles ----------------
// q,k,v layout: [B, T, H, HS] flat = row (b*T+t), col (h*64+e), stride DIM.
// One block per (query-tile, head, batch). P tile aliases the K tile (LDS cap).
__global__ __launch_bounds__(256) void attn_kernel(
    const float* __restrict__ q, const float* __restrict__ k,
    const float* __restrict__ v, float* __restrict__ o)
{
  __shared__ float QsT[64][68];   // QsT[d][row]
  __shared__ float KsT[64][68];   // KsT[d][key]; later reused as PsT[key][row]
  __shared__ float Vs[64][68];    // Vs[key][e]
  const int tid = threadIdx.x;
  const int qt = blockIdx.x, hh = blockIdx.y, bb = blockIdx.z;
  const int ty = tid >> 4, tx = tid & 15;
  const int lr = tid >> 2;            // 0..63 tile row for loads
  const int lq = (tid & 3) << 4;      // 0,16,32,48 col group for loads

  {
    const float* qb = q + (size_t)(bb * TT + qt * 64 + lr) * DIM + hh * 64 + lq;
#pragma unroll
    for (int u = 0; u < 4; ++u) {
      const float4 a = *(const float4*)(qb + u * 4);
      QsT[lq + u*4 + 0][lr] = a.x;
      QsT[lq + u*4 + 1][lr] = a.y;
      QsT[lq + u*4 + 2][lr] = a.z;
      QsT[lq + u*4 + 3][lr] = a.w;
    }
  }

  float oacc[4][4] = {};
  float mrow[4], lrow[4];
#pragma unroll
  for (int i = 0; i < 4; ++i) { mrow[i] = -INFINITY; lrow[i] = 0.f; }

  for (int kt = 0; kt <= qt; ++kt) {
    __syncthreads();   // Q stores visible (kt=0); prev PV reads done (kt>0)
    {
      const float* kbp = k + (size_t)(bb * TT + kt * 64 + lr) * DIM + hh * 64 + lq;
      const float* vbp = v + (size_t)(bb * TT + kt * 64 + lr) * DIM + hh * 64 + lq;
#pragma unroll
      for (int u = 0; u < 4; ++u) {
        const float4 a = *(const float4*)(kbp + u * 4);
        KsT[lq + u*4 + 0][lr] = a.x;
        KsT[lq + u*4 + 1][lr] = a.y;
        KsT[lq + u*4 + 2][lr] = a.z;
        KsT[lq + u*4 + 3][lr] = a.w;
        *(float4*)&Vs[lr][lq + u*4] = *(const float4*)(vbp + u * 4);
      }
    }
    __syncthreads();

    float s[4][4] = {};
#pragma unroll 8
    for (int d = 0; d < 64; ++d) {
      const float4 a = *(const float4*)&QsT[d][ty << 2];
      const float4 w = *(const float4*)&KsT[d][tx << 2];
      s[0][0] += a.x * w.x; s[0][1] += a.x * w.y; s[0][2] += a.x * w.z; s[0][3] += a.x * w.w;
      s[1][0] += a.y * w.x; s[1][1] += a.y * w.y; s[1][2] += a.y * w.z; s[1][3] += a.y * w.w;
      s[2][0] += a.z * w.x; s[2][1] += a.z * w.y; s[2][2] += a.z * w.z; s[2][3] += a.z * w.w;
      s[3][0] += a.w * w.x; s[3][1] += a.w * w.y; s[3][2] += a.w * w.z; s[3][3] += a.w * w.w;
    }

    const int tq0 = qt * 64 + (ty << 2);
    const int tk0 = kt * 64 + (tx << 2);
#pragma unroll
    for (int i = 0; i < 4; ++i)
#pragma unroll
      for (int j = 0; j < 4; ++j) {
        const float sv = s[i][j] * 0.125f;             // 1/sqrt(HS)
        s[i][j] = (tk0 + j > tq0 + i) ? -INFINITY : sv; // causal mask
      }

    float rmax[4];
#pragma unroll
    for (int i = 0; i < 4; ++i)
      rmax[i] = fmaxf(fmaxf(s[i][0], s[i][1]), fmaxf(s[i][2], s[i][3]));
#pragma unroll
    for (int off = 8; off > 0; off >>= 1)
#pragma unroll
      for (int i = 0; i < 4; ++i)
        rmax[i] = fmaxf(rmax[i], __shfl_xor(rmax[i], off, 64));

    float fac[4], psum[4];
#pragma unroll
    for (int i = 0; i < 4; ++i) {
      const float mnew = fmaxf(mrow[i], rmax[i]);
      fac[i] = expf(mrow[i] - mnew);    // first tile: exp(-inf)=0
      mrow[i] = mnew;
      float ps = 0.f;
#pragma unroll
      for (int j = 0; j < 4; ++j) {
        const float p = expf(s[i][j] - mnew);  // masked: exp(-inf)=0
        s[i][j] = p;
        ps += p;
      }
      psum[i] = ps;
    }
#pragma unroll
    for (int off = 8; off > 0; off >>= 1)
#pragma unroll
      for (int i = 0; i < 4; ++i)
        psum[i] += __shfl_xor(psum[i], off, 64);
#pragma unroll
    for (int i = 0; i < 4; ++i) {
      lrow[i] = lrow[i] * fac[i] + psum[i];
#pragma unroll
      for (int j = 0; j < 4; ++j) oacc[i][j] *= fac[i];
    }

    __syncthreads();   // everyone done reading KsT before P overwrites it
#pragma unroll
    for (int i = 0; i < 4; ++i)
#pragma unroll
      for (int j = 0; j < 4; ++j)
        KsT[(tx << 2) + j][(ty << 2) + i] = s[i][j];   // PsT[key][row]
    __syncthreads();

#pragma unroll 8
    for (int d = 0; d < 64; ++d) {
      const float4 p  = *(const float4*)&KsT[d][ty << 2];
      const float4 vv = *(const float4*)&Vs[d][tx << 2];
      oacc[0][0] += p.x * vv.x; oacc[0][1] += p.x * vv.y; oacc[0][2] += p.x * vv.z; oacc[0][3] += p.x * vv.w;
      oacc[1][0] += p.y * vv.x; oacc[1][1] += p.y * vv.y; oacc[1][2] += p.y * vv.z; oacc[1][3] += p.y * vv.w;
      oacc[2][0] += p.z * vv.x; oacc[2][1] += p.z * vv.y; oacc[2][2] += p.z * vv.z; oacc[2][3] += p.z * vv.w;
      oacc[3][0] += p.w * vv.x; oacc[3][1] += p.w * vv.y; oacc[3][2] += p.w * vv.z; oacc[3][3] += p.w * vv.w;
    }
  }

#pragma unroll
  for (int i = 0; i < 4; ++i) {
    const float inv = 1.0f / lrow[i];
    float4 vv;
    vv.x = oacc[i][0] * inv; vv.y = oacc[i][1] * inv;
    vv.z = oacc[i][2] * inv; vv.w = oacc[i][3] * inv;
    *(float4*)(o + (size_t)(bb * TT + qt * 64 + (ty << 2) + i) * DIM +
               hh * 64 + (tx << 2)) = vv;
  }
}

// ---------------- per-row cross-entropy: rloss[r] = -(logit_t - lse) --------
__global__ __launch_bounds__(256) void rowloss_kernel(
    const float* __restrict__ logits, const int* __restrict__ targets,
    float* __restrict__ rloss)
{
  __shared__ float sm[4];
  const int r = blockIdx.x, tid = threadIdx.x;
  const float* lr = logits + (size_t)r * VOCAB;
  float m = -INFINITY;
  for (int i = tid; i < VOCAB; i += 256) m = fmaxf(m, lr[i]);
#pragma unroll
  for (int o = 32; o > 0; o >>= 1) m = fmaxf(m, __shfl_down(m, o, 64));
  if ((tid & 63) == 0) sm[tid >> 6] = m;
  __syncthreads();
  m = fmaxf(fmaxf(sm[0], sm[1]), fmaxf(sm[2], sm[3]));
  __syncthreads();
  float ssum = 0.f;
  for (int i = tid; i < VOCAB; i += 256) ssum += expf(lr[i] - m);
  ssum = block_reduce_sum(ssum, sm);
  if (tid == 0) {
    const float lt = lr[targets[r]];
    rloss[r] = -(lt - m - logf(ssum));
  }
}

__global__ __launch_bounds__(256) void lossred_kernel(
    const float* __restrict__ rloss, float* __restrict__ out)
{
  __shared__ float sm[4];
  float s = 0.f;
  for (int i = threadIdx.x; i < BTOK; i += 256) s += rloss[i];
  s = block_reduce_sum(s, sm);
  if (threadIdx.x == 0) out[(size_t)BTOK * VOCAB] = s * (1.0f / BTOK);
}

// ---------------- driver ----------------
extern "C" void kernel_launch(void* const* d_in, const int* in_sizes, int n_in,
                              void* d_out, int out_size, void* d_ws, size_t ws_size,
                              hipStream_t stream)
{
  const int*   idx     = (const int*)d_in[0];
  const int*   targets = (const int*)d_in[1];
  const float* tok     = (const float*)d_in[2];
  const float* pos     = (const float*)d_in[3];
  const float* wq      = (const float*)d_in[4];
  const float* wk      = (const float*)d_in[5];
  const float* wv      = (const float*)d_in[6];
  const float* wo      = (const float*)d_in[7];
  const float* bo      = (const float*)d_in[8];
  const float* ln1s    = (const float*)d_in[9];
  const float* ln1b    = (const float*)d_in[10];
  const float* ln2s    = (const float*)d_in[11];
  const float* ln2b    = (const float*)d_in[12];
  const float* w1      = (const float*)d_in[13];
  const float* b1      = (const float*)d_in[14];
  const float* w2      = (const float*)d_in[15];
  const float* b2      = (const float*)d_in[16];
  const float* lnfs    = (const float*)d_in[17];
  const float* lnfb    = (const float*)d_in[18];
  const float* headw   = (const float*)d_in[19];
  const float* headb   = (const float*)d_in[20];
  float* logits = (float*)d_out;

  float* ws = (float*)d_ws;
  float* x    = ws; ws += (size_t)BTOK * DIM;
  float* hbuf = ws; ws += (size_t)BTOK * DIM;   // ln out; reused as attn out
  float* qb   = ws; ws += (size_t)BTOK * DIM;
  float* kb   = ws; ws += (size_t)BTOK * DIM;
  float* vb   = ws; ws += (size_t)BTOK * DIM;
  float* mlp  = ws; ws += (size_t)BTOK * DFF;
  float* rls  = ws; ws += BTOK;

  embed_kernel<<<BTOK, 192, 0, stream>>>(idx, tok, pos, x);

  const dim3 gD(BTOK / 64, DIM / 64);          // (64, 12)
  const dim3 gF(BTOK / 64, DFF / 64);          // (64, 48)
  const dim3 gH(BTOK / 64, (VOCAB + 63) / 64); // (64, 786)
  const dim3 ga(TT / 64, NH, BB);              // (32, 12, 2)

  for (int l = 0; l < NL; ++l) {
    ln_kernel<<<BTOK, 256, 0, stream>>>(x, ln1s + l * DIM, ln1b + l * DIM, hbuf);
    const float* wql = wq + (size_t)l * NH * DIM * HSZ;
    const float* wkl = wk + (size_t)l * NH * DIM * HSZ;
    const float* wvl = wv + (size_t)l * NH * DIM * HSZ;
    gemm_kernel<true,  false, false, false, false><<<gD, 256, 0, stream>>>(
        hbuf, wql, nullptr, nullptr, qb, BTOK, DIM, DIM);
    gemm_kernel<true,  false, false, false, false><<<gD, 256, 0, stream>>>(
        hbuf, wkl, nullptr, nullptr, kb, BTOK, DIM, DIM);
    gemm_kernel<true,  false, false, false, false><<<gD, 256, 0, stream>>>(
        hbuf, wvl, nullptr, nullptr, vb, BTOK, DIM, DIM);
    attn_kernel<<<ga, 256, 0, stream>>>(qb, kb, vb, hbuf);  // hbuf = attn out
    gemm_kernel<false, false, false, true,  true><<<gD, 256, 0, stream>>>(
        hbuf, wo + (size_t)l * DIM * DIM, bo + l * DIM, x, x, BTOK, DIM, DIM);
    ln_kernel<<<BTOK, 256, 0, stream>>>(x, ln2s + l * DIM, ln2b + l * DIM, hbuf);
    gemm_kernel<false, false, true,  false, true><<<gF, 256, 0, stream>>>(
        hbuf, w1 + (size_t)l * DIM * DFF, b1 + l * DFF, nullptr, mlp, BTOK, DFF, DIM);
    gemm_kernel<false, false, false, true,  true><<<gD, 256, 0, stream>>>(
        mlp, w2 + (size_t)l * DFF * DIM, b2 + l * DIM, x, x, BTOK, DIM, DFF);
  }

  ln_kernel<<<BTOK, 256, 0, stream>>>(x, lnfs, lnfb, hbuf);
  gemm_kernel<false, true, false, false, true><<<gH, 256, 0, stream>>>(
      hbuf, headw, headb, nullptr, logits, BTOK, VOCAB, DIM);
  rowloss_kernel<<<BTOK, 256, 0, stream>>>(logits, targets, rls);
  lossred_kernel<<<1, 256, 0, stream>>>(rls, logits);  // writes loss at [BTOK*VOCAB]
}